// Round 14
// baseline (3140.175 us; speedup 1.0000x reference)
//
#include <hip/hip_runtime.h>
#include <hip/hip_fp16.h>

// Persistent fused GRU + value head, MI355X (gfx950).
// T=512,B=256,I=64,H=512. 256 blocks x 128 threads = 16 batch groups x 16 slices
// x 2 MFMA waves. R14 = R13 (champion: packed flag line, fragment-major h slab)
// + split slab load: each wave loads HALF the group slab (8 x 1KB contiguous),
// shares via LDS (ds_write own half -> barrier -> ds_read other half) -> halves
// the dominant MALL transaction source (65k -> 33k lines/step). Service wave
// removed; X loaded directly by MFMA waves (L2-hot, hidden under poll).
// All cross-block state agent-scope at the MALL (sc0 sc1) — replay-safe.

#define T_  512
#define B_  256
#define I_  64
#define H_  512
#define NBG 16
#define BT  16                  // batch rows per group
#define HS  32                  // hidden units per block
#define BLOCK 128
#define NSL 32                  // value-head slices (j,wv)

typedef _Float16 f16;
typedef _Float16 f16x8 __attribute__((ext_vector_type(8)));
typedef float    f32x4 __attribute__((ext_vector_type(4)));
typedef unsigned int u32x2 __attribute__((ext_vector_type(2)));

__device__ __forceinline__ float sigmoid_f(float x) { return 1.f / (1.f + __expf(-x)); }
__device__ __forceinline__ float tanh_f(float x) {
    float e2 = __expf(2.f * x);
    return 1.f - 2.f / (e2 + 1.f);
}

__global__ __launch_bounds__(BLOCK, 1) void gru_persistent(
    const float* __restrict__ X, const float* __restrict__ Wih,
    const float* __restrict__ Whh, const float* __restrict__ bih,
    const float* __restrict__ bhh, const float* __restrict__ vw,
    const float* __restrict__ bias, float* __restrict__ Vout,
    f16* __restrict__ hbuf, unsigned int* __restrict__ flags,
    float* __restrict__ part, const int use_part)
{
    const int blk  = blockIdx.x;
    const int g    = (blk & 7) * 2 + (blk >> 7);   // group members share blk%8
    const int j    = (blk >> 3) & 15;
    const int b0   = g * BT;
    const int tid  = threadIdx.x;
    const int wv   = tid >> 6;                     // 0,1
    const int lane = tid & 63;
    const int quad = lane >> 4;
    const int mrow = lane & 15;

    __shared__ __align__(16) f16 sh_h[16][512];    // fragment-major slab share (16 KB)
    unsigned int* gflags = flags + (size_t)g * 32; // one 128B line per group

    // ============ stationary weights as A-operands: A[m=lane&15 -> unit][k=quad*8+e] ============
    f16x8 wh[3][16];
    f16x8 wxA[3][2];
    const int um = HS * j + wv * 16 + mrow;
    #pragma unroll
    for (int g3 = 0; g3 < 3; g3++) {
        const size_t grow = (size_t)(g3 * H_ + um);
        #pragma unroll
        for (int kt = 0; kt < 16; kt++) {
            const float* src = Whh + grow * H_ + kt * 32 + quad * 8;
            #pragma unroll
            for (int e = 0; e < 8; e++) wh[g3][kt][e] = (f16)src[e];
        }
        #pragma unroll
        for (int kt = 0; kt < 2; kt++) {
            const float* src = Wih + grow * I_ + kt * 32 + quad * 8;
            #pragma unroll
            for (int e = 0; e < 8; e++) wxA[g3][kt][e] = (f16)src[e];
        }
    }
    float b_r4[4], b_z4[4], b_ni4[4], b_nh4[4], vw4[4];
    #pragma unroll
    for (int r = 0; r < 4; r++) {
        const int ub = HS * j + wv * 16 + quad * 4 + r;
        b_r4[r]  = bih[ub] + bhh[ub];
        b_z4[r]  = bih[H_ + ub] + bhh[H_ + ub];
        b_ni4[r] = bih[2 * H_ + ub];
        b_nh4[r] = bhh[2 * H_ + ub];
        vw4[r]   = vw[ub];
    }
    float hprev[4] = {0.f, 0.f, 0.f, 0.f};   // fp32 anchor for z*h (t=0 zeros)
    unsigned int* myflag = gflags + (j * 2 + wv);
    const int sl = j * 2 + wv;
    const float bias0 = bias[0];

    #pragma unroll 1
    for (int t = 0; t < T_; t++) {
        // ---- X_t fragments (issued before poll; L2-hot: group-shared rows) ----
        const float* xb = X + (size_t)t * (B_ * I_) + (size_t)(b0 + mrow) * I_ + quad * 8;
        const f32x4 xv0 = *(const f32x4*)xb;
        const f32x4 xv1 = *(const f32x4*)(xb + 4);
        const f32x4 xv2 = *(const f32x4*)(xb + 32);
        const f32x4 xv3 = *(const f32x4*)(xb + 36);

        const f32x4 zero = {0.f, 0.f, 0.f, 0.f};
        f32x4 a_r = zero, a_z = zero, a_nh = zero;

        if (t > 0) {
            // ---- 1. ballot poll: one coalesced 128B line read per iteration ----
            {
                const unsigned target = (unsigned)t;
                for (;;) {
                    unsigned v = target;
                    if (lane < 32) {
                        const unsigned int* fp = gflags + lane;
                        asm volatile("global_load_dword %0, %1, off sc0 sc1\n\t"
                                     "s_waitcnt vmcnt(0)"
                                     : "=v"(v) : "v"(fp) : "memory");
                    }
                    if (__ballot(v >= target) == ~0ull) break;
                }
            }

            // ---- 2. own HALF of the slab: 8 x 1KB-contiguous loads ----
            f16x8 own[8];
            const char* pb = (const char*)(hbuf
                           + ((size_t)((t & 1) ^ 1) * NBG + g) * 8192)
                           + (size_t)wv * 8192 + quad * 256 + mrow * 16;
            asm volatile(
                "global_load_dwordx4 %0, %8, off sc0 sc1\n\t"
                "global_load_dwordx4 %1, %8, off offset:1024 sc0 sc1\n\t"
                "global_load_dwordx4 %2, %8, off offset:2048 sc0 sc1\n\t"
                "global_load_dwordx4 %3, %8, off offset:3072 sc0 sc1\n\t"
                "global_load_dwordx4 %4, %9, off sc0 sc1\n\t"
                "global_load_dwordx4 %5, %9, off offset:1024 sc0 sc1\n\t"
                "global_load_dwordx4 %6, %9, off offset:2048 sc0 sc1\n\t"
                "global_load_dwordx4 %7, %9, off offset:3072 sc0 sc1\n\t"
                "s_waitcnt vmcnt(0)"
                : "=&v"(own[0]), "=&v"(own[1]), "=&v"(own[2]), "=&v"(own[3]),
                  "=&v"(own[4]), "=&v"(own[5]), "=&v"(own[6]), "=&v"(own[7])
                : "v"(pb), "v"(pb + 4096)
                : "memory");

            // ---- 3. share: write own half to LDS, barrier, read other half ----
            {
                f16* dst = &sh_h[wv * 8][quad * 128 + mrow * 8];
                #pragma unroll
                for (int i = 0; i < 8; i++)
                    *(f16x8*)(dst + i * 512) = own[i];
            }
            __syncthreads();

            // own-half MFMAs first (ds_reads overlap them), kt = wv*8 + i
            #pragma unroll
            for (int i = 0; i < 8; i++) {
                const int kt = wv * 8 + i;
                a_r  = __builtin_amdgcn_mfma_f32_16x16x32_f16(wh[0][kt], own[i], a_r,  0, 0, 0);
                a_z  = __builtin_amdgcn_mfma_f32_16x16x32_f16(wh[1][kt], own[i], a_z,  0, 0, 0);
                a_nh = __builtin_amdgcn_mfma_f32_16x16x32_f16(wh[2][kt], own[i], a_nh, 0, 0, 0);
            }
            {
                const f16* src = &sh_h[(wv ^ 1) * 8][quad * 128 + mrow * 8];
                #pragma unroll
                for (int i = 0; i < 8; i++) {
                    const int kt = (wv ^ 1) * 8 + i;
                    const f16x8 hb = *(const f16x8*)(src + i * 512);
                    a_r  = __builtin_amdgcn_mfma_f32_16x16x32_f16(wh[0][kt], hb, a_r,  0, 0, 0);
                    a_z  = __builtin_amdgcn_mfma_f32_16x16x32_f16(wh[1][kt], hb, a_z,  0, 0, 0);
                    a_nh = __builtin_amdgcn_mfma_f32_16x16x32_f16(wh[2][kt], hb, a_nh, 0, 0, 0);
                }
            }
        }

        // ---- 4. x-projections (accumulate on top; fp32-assoc reorder is benign) ----
        f16x8 bx0, bx1;
        #pragma unroll
        for (int e = 0; e < 4; e++) {
            bx0[e] = (f16)xv0[e]; bx0[4 + e] = (f16)xv1[e];
            bx1[e] = (f16)xv2[e]; bx1[4 + e] = (f16)xv3[e];
        }
        f32x4 a_ni = __builtin_amdgcn_mfma_f32_16x16x32_f16(wxA[2][0], bx0, zero, 0, 0, 0);
        a_ni = __builtin_amdgcn_mfma_f32_16x16x32_f16(wxA[2][1], bx1, a_ni, 0, 0, 0);
        a_r  = __builtin_amdgcn_mfma_f32_16x16x32_f16(wxA[0][0], bx0, a_r,  0, 0, 0);
        a_r  = __builtin_amdgcn_mfma_f32_16x16x32_f16(wxA[0][1], bx1, a_r,  0, 0, 0);
        a_z  = __builtin_amdgcn_mfma_f32_16x16x32_f16(wxA[1][0], bx0, a_z,  0, 0, 0);
        a_z  = __builtin_amdgcn_mfma_f32_16x16x32_f16(wxA[1][1], bx1, a_z,  0, 0, 0);

        // ---- 5. gates in registers; one 8B fragment-major h-store/lane ----
        float hn[4];
        union { f16 h[4]; u32x2 v; } pk;
        #pragma unroll
        for (int r = 0; r < 4; r++) {     // D: row=quad*4+r -> unit, col=mrow -> batch
            float rg = sigmoid_f(a_r[r] + b_r4[r]);
            float zg = sigmoid_f(a_z[r] + b_z4[r]);
            float ng = tanh_f(a_ni[r] + b_ni4[r] + rg * (a_nh[r] + b_nh4[r]));
            hn[r] = (1.f - zg) * ng + zg * hprev[r];
            hprev[r] = hn[r];
            pk.h[r] = (f16)hn[r];
        }
        {
            // h[batch=mrow][u=32j+16wv+4quad+r] -> idx=(u>>3)*128 + mrow*8 + (u&7)
            f16* hp = hbuf + ((size_t)(t & 1) * NBG + g) * 8192
                    + (size_t)((4 * j + 2 * wv + (quad >> 1)) * 128
                               + mrow * 8 + (quad & 1) * 4);
            asm volatile("global_store_dwordx2 %0, %1, off sc0 sc1"
                         :: "v"(hp), "v"(pk.v) : "memory");
        }
        // value-head partial overlaps the store's flight time
        float s = hn[0] * vw4[0] + hn[1] * vw4[1] + hn[2] * vw4[2] + hn[3] * vw4[3];
        s += __shfl_xor(s, 16);
        s += __shfl_xor(s, 32);

        asm volatile("s_waitcnt vmcnt(0)" ::: "memory");   // h at MALL before flag
        if (lane == 0)
            __hip_atomic_store(myflag, (unsigned)(t + 1),
                               __ATOMIC_RELAXED, __HIP_MEMORY_SCOPE_AGENT);
        if (quad == 0) {
            if (use_part) part[(size_t)sl * (T_ * B_) + (size_t)t * B_ + b0 + mrow] = s;
            else atomicAdd(&Vout[(size_t)t * B_ + b0 + mrow], s + (sl == 0 ? bias0 : 0.f));
        }
        // No second barrier: wave B's step-t+1 ds_write is gated by wave A's
        // flag=t+1, which A sets only after its MFMAs consumed the step-t reads.
    }
}

__global__ __launch_bounds__(256) void value_reduce(
    const float* __restrict__ part, const float* __restrict__ bias,
    float* __restrict__ Vout)
{
    const int i = blockIdx.x * 256 + threadIdx.x;   // i < T_*B_
    float s = bias[0];
    #pragma unroll
    for (int sl = 0; sl < NSL; sl++) s += part[(size_t)sl * (T_ * B_) + i];
    Vout[i] = s;
}

extern "C" void kernel_launch(void* const* d_in, const int* in_sizes, int n_in,
                              void* d_out, int out_size, void* d_ws, size_t ws_size,
                              hipStream_t stream) {
    const float* X    = (const float*)d_in[0];
    const float* Wih  = (const float*)d_in[1];
    const float* Whh  = (const float*)d_in[2];
    const float* bih  = (const float*)d_in[3];
    const float* bhh  = (const float*)d_in[4];
    const float* vw   = (const float*)d_in[5];
    const float* bias = (const float*)d_in[6];
    float* Vout = (float*)d_out;

    f16* hbuf = (f16*)d_ws;                                            // no init needed
    const size_t hbytes    = (size_t)2 * B_ * H_ * sizeof(f16);        // 512 KB
    const size_t flagbytes = (size_t)NBG * 32 * sizeof(unsigned);      // 2 KB (1 line/group)
    unsigned int* flags = (unsigned int*)((char*)d_ws + hbytes);
    float* part = (float*)((char*)d_ws + hbytes + flagbytes);
    const size_t partbytes = (size_t)NSL * T_ * B_ * sizeof(float);    // 16.8 MB
    const int use_part = (ws_size >= hbytes + flagbytes + partbytes) ? 1 : 0;

    hipMemsetAsync(flags, 0, flagbytes, stream);   // flags at MALL: replay-safe reset
    if (!use_part)
        hipMemsetAsync(d_out, 0, (size_t)out_size * sizeof(float), stream);

    gru_persistent<<<256, BLOCK, 0, stream>>>(X, Wih, Whh, bih, bhh, vw, bias,
                                              Vout, hbuf, flags, part, use_part);
    if (use_part)
        value_reduce<<<(T_ * B_) / 256, 256, 0, stream>>>(part, bias, Vout);
}